// Round 1
// baseline (946.353 us; speedup 1.0000x reference)
//
#include <hip/hip_runtime.h>

// ---- problem constants ----
#define D_DIM 1024
#define E_EXP 8
#define M_DIM 4096
#define N_GRP 8
#define GRP_SZ 1024
#define CAPACITY 256
#define N_TOK (N_GRP * GRP_SZ)                 // 8192 tokens
#define SLOT_ROWS (E_EXP * N_GRP * CAPACITY)   // 16384 expert-slot rows
#define ROWS_PER_E (N_GRP * CAPACITY)          // 2048 rows per expert

typedef _Float16 half8_t __attribute__((ext_vector_type(8)));
typedef float f32x4_t __attribute__((ext_vector_type(4)));

__device__ __forceinline__ void async_copy16(void* lds, const void* gptr) {
  __builtin_amdgcn_global_load_lds(
      (__attribute__((address_space(1))) void*)(void*)(const_cast<void*>(gptr)),
      (__attribute__((address_space(3))) void*)lds,
      16, 0, 0);
}

// ---------------- router: logits -> softmax -> top2 ----------------
__global__ __launch_bounds__(256)
void router_kernel(const float* __restrict__ x, const float* __restrict__ wr,
                   float* __restrict__ gates, int* __restrict__ tk_idx,
                   float* __restrict__ tk_val) {
  __shared__ __attribute__((aligned(16))) float wrT[E_EXP * D_DIM];
  const int tid = threadIdx.x;
  for (int i = tid; i < E_EXP * D_DIM; i += 256) {
    int d = i >> 3, e = i & 7;
    wrT[e * D_DIM + d] = wr[i];
  }
  __syncthreads();
  const int wv = tid >> 6, lane = tid & 63;
  const int token = blockIdx.x * 4 + wv;   // one wave per token
  const float4* xr = (const float4*)(x + (size_t)token * D_DIM);
  float lg[8] = {0.f, 0.f, 0.f, 0.f, 0.f, 0.f, 0.f, 0.f};
#pragma unroll
  for (int it = 0; it < 4; it++) {
    float4 v = xr[it * 64 + lane];
#pragma unroll
    for (int e = 0; e < 8; e++) {
      float4 w = *(const float4*)&wrT[e * D_DIM + (it * 64 + lane) * 4];
      lg[e] += v.x * w.x + v.y * w.y + v.z * w.z + v.w * w.w;
    }
  }
#pragma unroll
  for (int off = 32; off > 0; off >>= 1) {
#pragma unroll
    for (int e = 0; e < 8; e++) lg[e] += __shfl_xor(lg[e], off, 64);
  }
  if (lane == 0) {
    float mx = lg[0];
#pragma unroll
    for (int e = 1; e < 8; e++) mx = fmaxf(mx, lg[e]);
    float s = 0.f, g[8];
#pragma unroll
    for (int e = 0; e < 8; e++) { g[e] = expf(lg[e] - mx); s += g[e]; }
    float inv = 1.0f / s;
#pragma unroll
    for (int e = 0; e < 8; e++) { g[e] *= inv; gates[(size_t)token * 8 + e] = g[e]; }
    // stable top-2 (strict > keeps lowest index on ties, matching jax.lax.top_k)
    int i0 = 0; float v0 = g[0];
    for (int e = 1; e < 8; e++) if (g[e] > v0) { v0 = g[e]; i0 = e; }
    int i1 = -1; float v1 = -1.f;
    for (int e = 0; e < 8; e++) if (e != i0 && g[e] > v1) { v1 = g[e]; i1 = e; }
    tk_idx[token * 2 + 0] = i0; tk_idx[token * 2 + 1] = i1;
    tk_val[token * 2 + 0] = v0; tk_val[token * 2 + 1] = v1;
  }
}

// ---------------- capacity scan: exact reference semantics ----------------
// positions = unclamped running count, k-major then s-minor; keep iff pos < CAP
__global__ void scan_kernel(const int* __restrict__ tk_idx,
                            int* __restrict__ slot_src,
                            int* __restrict__ assign_row) {
  const int g = blockIdx.x;
  const int lane = threadIdx.x;  // 64 threads = 1 wave
  const unsigned long long below = (1ull << lane) - 1ull;
  int cnt[8] = {0, 0, 0, 0, 0, 0, 0, 0};
  for (int k = 0; k < 2; k++) {
    for (int ch = 0; ch < 16; ch++) {
      const int s = ch * 64 + lane;
      const int e = tk_idx[((size_t)g * GRP_SZ + s) * 2 + k];
      int pos = 0;
#pragma unroll
      for (int ee = 0; ee < 8; ee++) {
        unsigned long long m = __ballot(e == ee);
        if (e == ee) pos = cnt[ee] + (int)__popcll(m & below);
        cnt[ee] += (int)__popcll(m);   // unclamped (matches reference prev)
      }
      int row = (pos < CAPACITY) ? ((e * N_GRP + g) * CAPACITY + pos) : -1;
      assign_row[((size_t)g * GRP_SZ + s) * 2 + k] = row;
      if (row >= 0) slot_src[row] = s;
    }
  }
  // mark empty slots
  for (int e = 0; e < 8; e++)
    for (int c = lane; c < CAPACITY; c += 64)
      if (c >= cnt[e]) slot_src[(e * N_GRP + g) * CAPACITY + c] = -1;
}

// ---------------- gather tokens into fp16 expert rows ----------------
__global__ __launch_bounds__(256)
void gather_kernel(const float* __restrict__ x, const int* __restrict__ slot_src,
                   _Float16* __restrict__ A1) {
  const int row = blockIdx.x;          // 0..16383 = (e*8+g)*256+c
  const int g = (row >> 8) & 7;
  const int t = threadIdx.x;
  const int s = slot_src[row];
  float2* dst = (float2*)(A1 + (size_t)row * D_DIM);
  if (s < 0) { dst[t] = make_float2(0.f, 0.f); return; }
  const float4 v = ((const float4*)x)[((size_t)g * GRP_SZ + s) * (D_DIM / 4) + t];
  union { _Float16 h[4]; float2 f2; } u;
  u.h[0] = (_Float16)v.x; u.h[1] = (_Float16)v.y;
  u.h[2] = (_Float16)v.z; u.h[3] = (_Float16)v.w;
  dst[t] = u.f2;
}

// ---------------- fp32 (E,R,C) -> fp16 (E,C,R) transpose ----------------
__global__ __launch_bounds__(256)
void transpose_to_fp16_kernel(const float* __restrict__ src, _Float16* __restrict__ dst,
                              int R, int C) {
  __shared__ float tile[32][33];
  const int e = blockIdx.z;
  const int c0 = blockIdx.x * 32, r0 = blockIdx.y * 32;
  const int tx = threadIdx.x & 31, ty = threadIdx.x >> 5;  // 32x8
  const float* sp = src + (size_t)e * R * C;
  _Float16* dp = dst + (size_t)e * R * C;
#pragma unroll
  for (int i = 0; i < 32; i += 8)
    tile[ty + i][tx] = sp[(size_t)(r0 + ty + i) * C + (c0 + tx)];
  __syncthreads();
#pragma unroll
  for (int i = 0; i < 32; i += 8)
    dp[(size_t)(c0 + ty + i) * R + (r0 + tx)] = (_Float16)tile[tx][ty + i];
}

// ---------------- MFMA GEMM: C(2048xN) = A(2048xK) * BT(NxK)^T ----------------
// 128x128 tile, BK=32, 4 waves x (4x4) mfma_f32_16x16x32_f16.
// global_load_lds (16B/lane) with XOR chunk swizzle: LDS slot s holds global
// k-chunk q = s ^ ((row>>1)&3) so fragment ds_read_b128 is bank-balanced.
// EPI==1: gelu(acc+bias) -> fp16 store (H).  EPI==2: acc+bias -> fp32 (ye).
template <int KDIM, int NDIM, int EPI>
__global__ __launch_bounds__(256)
void gemm_bt_kernel(const _Float16* __restrict__ Aall,
                    const _Float16* __restrict__ BTall,
                    const float* __restrict__ biasAll,
                    void* __restrict__ CoutAll) {
  const int e = blockIdx.z;
  const _Float16* A = Aall + (size_t)e * ROWS_PER_E * KDIM;
  const _Float16* BT = BTall + (size_t)e * NDIM * KDIM;
  const float* bias = biasAll + (size_t)e * NDIM;

  const int tid = threadIdx.x;
  const int wave = tid >> 6, lane = tid & 63;
  const int wm = (wave & 1) * 64, wn = (wave >> 1) * 64;

  __shared__ __attribute__((aligned(16))) _Float16 As[128 * 32];
  __shared__ __attribute__((aligned(16))) _Float16 Bs[128 * 32];

  f32x4_t acc[4][4] = {};

  // staging: issue0 row = wave*16 + lane/4, issue1 = +64; slot = lane&3
  const int lrow = lane >> 2, lslot = lane & 3;
  const int rA = wave * 16 + lrow;
  const int rB = rA + 64;
  const int qA = lslot ^ ((rA >> 1) & 3);
  const int qB = lslot ^ ((rB >> 1) & 3);
  const _Float16* gA0 = A + (size_t)(blockIdx.x * 128 + rA) * KDIM + qA * 8;
  const _Float16* gA1 = A + (size_t)(blockIdx.x * 128 + rB) * KDIM + qB * 8;
  const _Float16* gB0 = BT + (size_t)(blockIdx.y * 128 + rA) * KDIM + qA * 8;
  const _Float16* gB1 = BT + (size_t)(blockIdx.y * 128 + rB) * KDIM + qB * 8;
  _Float16* ldsA0 = &As[(wave * 16) * 32];
  _Float16* ldsA1 = &As[(64 + wave * 16) * 32];
  _Float16* ldsB0 = &Bs[(wave * 16) * 32];
  _Float16* ldsB1 = &Bs[(64 + wave * 16) * 32];

  // fragment LDS element offsets (A: m=lane&15, k=quad*8+j ; B mirrors with n)
  const int quad = lane >> 4;
  int offA[4], offB[4];
#pragma unroll
  for (int i = 0; i < 4; i++) {
    int m = wm + i * 16 + (lane & 15);
    offA[i] = m * 32 + (quad ^ ((m >> 1) & 3)) * 8;
    int n = wn + i * 16 + (lane & 15);
    offB[i] = n * 32 + (quad ^ ((n >> 1) & 3)) * 8;
  }

  for (int kt = 0; kt < KDIM; kt += 32) {
    __syncthreads();  // previous iter's LDS reads complete
    async_copy16(ldsA0, gA0 + kt);
    async_copy16(ldsA1, gA1 + kt);
    async_copy16(ldsB0, gB0 + kt);
    async_copy16(ldsB1, gB1 + kt);
    __syncthreads();  // drains vmcnt: tiles visible
    half8_t af[4], bf[4];
#pragma unroll
    for (int i = 0; i < 4; i++) {
      af[i] = *(const half8_t*)&As[offA[i]];
      bf[i] = *(const half8_t*)&Bs[offB[i]];
    }
#pragma unroll
    for (int i = 0; i < 4; i++)
#pragma unroll
      for (int j = 0; j < 4; j++)
        acc[i][j] = __builtin_amdgcn_mfma_f32_16x16x32_f16(af[i], bf[j], acc[i][j], 0, 0, 0);
  }

  // epilogue: C/D layout col = lane&15, row = quad*4 + reg
  const int colb = blockIdx.y * 128 + wn + (lane & 15);
  const int rowb = blockIdx.x * 128 + wm + quad * 4;
  if constexpr (EPI == 1) {
    _Float16* C = (_Float16*)CoutAll + (size_t)e * ROWS_PER_E * NDIM;
#pragma unroll
    for (int j = 0; j < 4; j++) {
      const int col = colb + j * 16;
      const float bcol = bias[col];
#pragma unroll
      for (int i = 0; i < 4; i++) {
#pragma unroll
        for (int r = 0; r < 4; r++) {
          const int row = rowb + i * 16 + r;
          float v = acc[i][j][r] + bcol;
          // jax.nn.gelu approximate=True (tanh form)
          float t = tanhf(0.79788456080286536f * (v + 0.044715f * v * v * v));
          C[(size_t)row * NDIM + col] = (_Float16)(0.5f * v * (1.0f + t));
        }
      }
    }
  } else {
    float* C = (float*)CoutAll + (size_t)e * ROWS_PER_E * NDIM;
#pragma unroll
    for (int j = 0; j < 4; j++) {
      const int col = colb + j * 16;
      const float bcol = bias[col];
#pragma unroll
      for (int i = 0; i < 4; i++) {
#pragma unroll
        for (int r = 0; r < 4; r++) {
          const int row = rowb + i * 16 + r;
          C[(size_t)row * NDIM + col] = acc[i][j][r] + bcol;
        }
      }
    }
  }
}

// ---------------- gated combine scatter ----------------
__global__ __launch_bounds__(256)
void combine_kernel(const float* __restrict__ ye, const int* __restrict__ assign_row,
                    const float* __restrict__ tk_val, float* __restrict__ out) {
  const int t = blockIdx.x;     // token
  const int d = threadIdx.x;    // float4 lane
  const int r0 = assign_row[t * 2 + 0];
  const int r1 = assign_row[t * 2 + 1];
  const float g0 = tk_val[t * 2 + 0];
  const float g1 = tk_val[t * 2 + 1];
  const float4* y4 = (const float4*)ye;
  float4 v = make_float4(0.f, 0.f, 0.f, 0.f);
  if (r0 >= 0) {
    float4 a = y4[(size_t)r0 * (D_DIM / 4) + d];
    v.x += g0 * a.x; v.y += g0 * a.y; v.z += g0 * a.z; v.w += g0 * a.w;
  }
  if (r1 >= 0) {
    float4 a = y4[(size_t)r1 * (D_DIM / 4) + d];
    v.x += g1 * a.x; v.y += g1 * a.y; v.z += g1 * a.z; v.w += g1 * a.w;
  }
  ((float4*)out)[(size_t)t * (D_DIM / 4) + d] = v;
}

// ---------------- aux scalar ----------------
__global__ void aux_kernel(const float* __restrict__ gates, float* __restrict__ aux_out) {
  __shared__ float impS[64];
  __shared__ float cvS[8];
  const int t = threadIdx.x;           // 256
  const int pair = t >> 2, part = t & 3;
  const int g = pair >> 3, e = pair & 7;
  float sum = 0.f;
  for (int s = part; s < GRP_SZ; s += 4)
    sum += gates[((size_t)g * GRP_SZ + s) * 8 + e];
  sum += __shfl_down(sum, 1, 64);
  sum += __shfl_down(sum, 2, 64);
  if (part == 0) impS[pair] = sum;
  __syncthreads();
  if (t < 8) {
    float mean = 0.f;
    for (int k = 0; k < 8; k++) mean += impS[t * 8 + k];
    mean *= 0.125f;
    float var = 0.f;
    for (int k = 0; k < 8; k++) { float dd = impS[t * 8 + k] - mean; var += dd * dd; }
    var *= 0.125f;
    cvS[t] = var / (mean * mean);
  }
  __syncthreads();
  if (t == 0) {
    float a = 0.f;
    for (int k = 0; k < 8; k++) a += cvS[k];
    aux_out[0] = a * 0.125f;
  }
}

extern "C" void kernel_launch(void* const* d_in, const int* in_sizes, int n_in,
                              void* d_out, int out_size, void* d_ws, size_t ws_size,
                              hipStream_t stream) {
  const float* x  = (const float*)d_in[0];
  const float* wr = (const float*)d_in[1];
  const float* w1 = (const float*)d_in[2];
  const float* b1 = (const float*)d_in[3];
  const float* w2 = (const float*)d_in[4];
  const float* b2 = (const float*)d_in[5];
  float* out = (float*)d_out;

  char* ws = (char*)d_ws;
  size_t off = 0;
  auto alloc = [&](size_t bytes) -> void* {
    void* p = ws + off;
    off += (bytes + 255) & ~(size_t)255;
    return p;
  };
  float*     gates      = (float*)alloc((size_t)N_TOK * 8 * 4);
  int*       tk_idx     = (int*)  alloc((size_t)N_TOK * 2 * 4);
  float*     tk_val     = (float*)alloc((size_t)N_TOK * 2 * 4);
  int*       assign_row = (int*)  alloc((size_t)N_TOK * 2 * 4);
  int*       slot_src   = (int*)  alloc((size_t)SLOT_ROWS * 4);
  _Float16*  A1  = (_Float16*)alloc((size_t)SLOT_ROWS * D_DIM * 2);   //  33.5 MB
  _Float16*  w1t = (_Float16*)alloc((size_t)E_EXP * M_DIM * D_DIM * 2); // 67 MB
  _Float16*  w2t = (_Float16*)alloc((size_t)E_EXP * D_DIM * M_DIM * 2); // 67 MB
  _Float16*  H   = (_Float16*)alloc((size_t)SLOT_ROWS * M_DIM * 2);   // 134 MB
  float*     ye  = (float*)   alloc((size_t)SLOT_ROWS * D_DIM * 4);   //  67 MB
  if (off > ws_size) return;  // workspace too small: fail validation cleanly

  router_kernel<<<N_TOK / 4, 256, 0, stream>>>(x, wr, gates, tk_idx, tk_val);
  scan_kernel<<<N_GRP, 64, 0, stream>>>(tk_idx, slot_src, assign_row);
  gather_kernel<<<SLOT_ROWS, 256, 0, stream>>>(x, slot_src, A1);
  transpose_to_fp16_kernel<<<dim3(M_DIM / 32, D_DIM / 32, E_EXP), 256, 0, stream>>>(w1, w1t, D_DIM, M_DIM);
  transpose_to_fp16_kernel<<<dim3(D_DIM / 32, M_DIM / 32, E_EXP), 256, 0, stream>>>(w2, w2t, M_DIM, D_DIM);
  gemm_bt_kernel<D_DIM, M_DIM, 1><<<dim3(ROWS_PER_E / 128, M_DIM / 128, E_EXP), 256, 0, stream>>>(A1, w1t, b1, H);
  gemm_bt_kernel<M_DIM, D_DIM, 2><<<dim3(ROWS_PER_E / 128, D_DIM / 128, E_EXP), 256, 0, stream>>>(H, w2t, b2, ye);
  combine_kernel<<<N_TOK, 256, 0, stream>>>(ye, assign_row, tk_val, out);
  aux_kernel<<<1, 256, 0, stream>>>(gates, out + (size_t)N_TOK * D_DIM);
}

// Round 2
// 911.525 us; speedup vs baseline: 1.0382x; 1.0382x over previous
//
#include <hip/hip_runtime.h>

// ---- problem constants ----
#define D_DIM 1024
#define E_EXP 8
#define M_DIM 4096
#define N_GRP 8
#define GRP_SZ 1024
#define CAPACITY 256
#define N_TOK (N_GRP * GRP_SZ)                 // 8192 tokens
#define SLOT_ROWS (E_EXP * N_GRP * CAPACITY)   // 16384 expert-slot rows
#define ROWS_PER_E (N_GRP * CAPACITY)          // 2048 rows per expert

typedef _Float16 half8_t __attribute__((ext_vector_type(8)));
typedef float f32x4_t __attribute__((ext_vector_type(4)));

__device__ __forceinline__ void async_copy16(void* lds, const void* gptr) {
  __builtin_amdgcn_global_load_lds(
      (__attribute__((address_space(1))) void*)(void*)(const_cast<void*>(gptr)),
      (__attribute__((address_space(3))) void*)lds,
      16, 0, 0);
}

// fast exact-form tanh-gelu: tanh(w) = 1 - 2/(1+e^{2w}); e^x via v_exp_f32
__device__ __forceinline__ float fast_gelu(float v) {
  float w2 = 1.5957691216057308f * (v + 0.044715f * v * v * v);  // 2*0.79788456*(...)
  float ex = __expf(w2);
  float t = 1.0f - 2.0f * __builtin_amdgcn_rcpf(1.0f + ex);
  return 0.5f * v * (1.0f + t);
}

// ---------------- router: logits -> softmax -> top2 ----------------
__global__ __launch_bounds__(256)
void router_kernel(const float* __restrict__ x, const float* __restrict__ wr,
                   float* __restrict__ gates, int* __restrict__ tk_idx,
                   float* __restrict__ tk_val) {
  __shared__ __attribute__((aligned(16))) float wrT[E_EXP * D_DIM];
  const int tid = threadIdx.x;
  for (int i = tid; i < E_EXP * D_DIM; i += 256) {
    int d = i >> 3, e = i & 7;
    wrT[e * D_DIM + d] = wr[i];
  }
  __syncthreads();
  const int wv = tid >> 6, lane = tid & 63;
  const int token = blockIdx.x * 4 + wv;   // one wave per token
  const float4* xr = (const float4*)(x + (size_t)token * D_DIM);
  float lg[8] = {0.f, 0.f, 0.f, 0.f, 0.f, 0.f, 0.f, 0.f};
#pragma unroll
  for (int it = 0; it < 4; it++) {
    float4 v = xr[it * 64 + lane];
#pragma unroll
    for (int e = 0; e < 8; e++) {
      float4 w = *(const float4*)&wrT[e * D_DIM + (it * 64 + lane) * 4];
      lg[e] += v.x * w.x + v.y * w.y + v.z * w.z + v.w * w.w;
    }
  }
#pragma unroll
  for (int off = 32; off > 0; off >>= 1) {
#pragma unroll
    for (int e = 0; e < 8; e++) lg[e] += __shfl_xor(lg[e], off, 64);
  }
  if (lane == 0) {
    float mx = lg[0];
#pragma unroll
    for (int e = 1; e < 8; e++) mx = fmaxf(mx, lg[e]);
    float s = 0.f, g[8];
#pragma unroll
    for (int e = 0; e < 8; e++) { g[e] = expf(lg[e] - mx); s += g[e]; }
    float inv = 1.0f / s;
#pragma unroll
    for (int e = 0; e < 8; e++) { g[e] *= inv; gates[(size_t)token * 8 + e] = g[e]; }
    // stable top-2 (strict > keeps lowest index on ties, matching jax.lax.top_k)
    int i0 = 0; float v0 = g[0];
    for (int e = 1; e < 8; e++) if (g[e] > v0) { v0 = g[e]; i0 = e; }
    int i1 = -1; float v1 = -1.f;
    for (int e = 0; e < 8; e++) if (e != i0 && g[e] > v1) { v1 = g[e]; i1 = e; }
    tk_idx[token * 2 + 0] = i0; tk_idx[token * 2 + 1] = i1;
    tk_val[token * 2 + 0] = v0; tk_val[token * 2 + 1] = v1;
  }
}

// ---------------- capacity scan: exact reference semantics ----------------
__global__ void scan_kernel(const int* __restrict__ tk_idx,
                            int* __restrict__ slot_src,
                            int* __restrict__ assign_row) {
  const int g = blockIdx.x;
  const int lane = threadIdx.x;  // 64 threads = 1 wave
  const unsigned long long below = (1ull << lane) - 1ull;
  int cnt[8] = {0, 0, 0, 0, 0, 0, 0, 0};
  for (int k = 0; k < 2; k++) {
    for (int ch = 0; ch < 16; ch++) {
      const int s = ch * 64 + lane;
      const int e = tk_idx[((size_t)g * GRP_SZ + s) * 2 + k];
      int pos = 0;
#pragma unroll
      for (int ee = 0; ee < 8; ee++) {
        unsigned long long m = __ballot(e == ee);
        if (e == ee) pos = cnt[ee] + (int)__popcll(m & below);
        cnt[ee] += (int)__popcll(m);   // unclamped (matches reference prev)
      }
      int row = (pos < CAPACITY) ? ((e * N_GRP + g) * CAPACITY + pos) : -1;
      assign_row[((size_t)g * GRP_SZ + s) * 2 + k] = row;
      if (row >= 0) slot_src[row] = s;
    }
  }
  for (int e = 0; e < 8; e++)
    for (int c = lane; c < CAPACITY; c += 64)
      if (c >= cnt[e]) slot_src[(e * N_GRP + g) * CAPACITY + c] = -1;
}

// ---------------- gather tokens into fp16 expert rows ----------------
__global__ __launch_bounds__(256)
void gather_kernel(const float* __restrict__ x, const int* __restrict__ slot_src,
                   _Float16* __restrict__ A1) {
  const int row = blockIdx.x;
  const int g = (row >> 8) & 7;
  const int t = threadIdx.x;
  const int s = slot_src[row];
  float2* dst = (float2*)(A1 + (size_t)row * D_DIM);
  if (s < 0) { dst[t] = make_float2(0.f, 0.f); return; }
  const float4 v = ((const float4*)x)[((size_t)g * GRP_SZ + s) * (D_DIM / 4) + t];
  union { _Float16 h[4]; float2 f2; } u;
  u.h[0] = (_Float16)v.x; u.h[1] = (_Float16)v.y;
  u.h[2] = (_Float16)v.z; u.h[3] = (_Float16)v.w;
  dst[t] = u.f2;
}

// ---------------- fp32 (E,R,C) -> fp16 (E,C,R) transpose, 8B stores ----------------
__global__ __launch_bounds__(256)
void transpose_to_fp16_kernel(const float* __restrict__ src, _Float16* __restrict__ dst,
                              int R, int C) {
  __shared__ float tile[32][33];
  const int e = blockIdx.z;
  const int c0 = blockIdx.x * 32, r0 = blockIdx.y * 32;
  const int tx = threadIdx.x & 31, ty = threadIdx.x >> 5;  // 32x8 read shape
  const float* sp = src + (size_t)e * R * C;
  _Float16* dp = dst + (size_t)e * R * C;
#pragma unroll
  for (int i = 0; i < 32; i += 8)
    tile[ty + i][tx] = sp[(size_t)(r0 + ty + i) * C + (c0 + tx)];
  __syncthreads();
  const int cl = threadIdx.x >> 3;   // 0..31: output row (c)
  const int ch = threadIdx.x & 7;    // chunk of 4 fp16
  union { _Float16 h[4]; float2 f2; } u;
#pragma unroll
  for (int k = 0; k < 4; k++) u.h[k] = (_Float16)tile[ch * 4 + k][cl];
  *(float2*)&dp[(size_t)(c0 + cl) * R + r0 + ch * 4] = u.f2;
}

// ---------------- MFMA GEMM: C(2048xN) = A(2048xK) * BT(NxK)^T ----------------
// 128x128 tile, BK=32, 4 waves x (4x4) mfma_f32_16x16x32_f16.
// EPI==1: fast-gelu(acc+bias) -> LDS-staged coalesced fp16 store (H).
// EPI==2: acc+bias -> fp32 direct store (ye).
template <int KDIM, int NDIM, int EPI>
__global__ __launch_bounds__(256)
void gemm_bt_kernel(const _Float16* __restrict__ Aall,
                    const _Float16* __restrict__ BTall,
                    const float* __restrict__ biasAll,
                    void* __restrict__ CoutAll) {
  const int e = blockIdx.z;
  const _Float16* A = Aall + (size_t)e * ROWS_PER_E * KDIM;
  const _Float16* BT = BTall + (size_t)e * NDIM * KDIM;
  const float* bias = biasAll + (size_t)e * NDIM;

  const int tid = threadIdx.x;
  const int wave = tid >> 6, lane = tid & 63;
  const int wm = (wave & 1) * 64, wn = (wave >> 1) * 64;

  __shared__ __attribute__((aligned(16))) _Float16 smem[2 * 128 * 32];  // 16 KB
  _Float16* As = smem;
  _Float16* Bs = smem + 128 * 32;

  f32x4_t acc[4][4] = {};

  const int lrow = lane >> 2, lslot = lane & 3;
  const int rA = wave * 16 + lrow;
  const int rB = rA + 64;
  const int qA = lslot ^ ((rA >> 1) & 3);
  const int qB = lslot ^ ((rB >> 1) & 3);
  const _Float16* gA0 = A + (size_t)(blockIdx.x * 128 + rA) * KDIM + qA * 8;
  const _Float16* gA1 = A + (size_t)(blockIdx.x * 128 + rB) * KDIM + qB * 8;
  const _Float16* gB0 = BT + (size_t)(blockIdx.y * 128 + rA) * KDIM + qA * 8;
  const _Float16* gB1 = BT + (size_t)(blockIdx.y * 128 + rB) * KDIM + qB * 8;
  _Float16* ldsA0 = &As[(wave * 16) * 32];
  _Float16* ldsA1 = &As[(64 + wave * 16) * 32];
  _Float16* ldsB0 = &Bs[(wave * 16) * 32];
  _Float16* ldsB1 = &Bs[(64 + wave * 16) * 32];

  const int quad = lane >> 4;
  const int ln = lane & 15;
  int offA[4], offB[4];
#pragma unroll
  for (int i = 0; i < 4; i++) {
    int m = wm + i * 16 + ln;
    offA[i] = m * 32 + (quad ^ ((m >> 1) & 3)) * 8;
    int n = wn + i * 16 + ln;
    offB[i] = n * 32 + (quad ^ ((n >> 1) & 3)) * 8;
  }

  for (int kt = 0; kt < KDIM; kt += 32) {
    __syncthreads();
    async_copy16(ldsA0, gA0 + kt);
    async_copy16(ldsA1, gA1 + kt);
    async_copy16(ldsB0, gB0 + kt);
    async_copy16(ldsB1, gB1 + kt);
    __syncthreads();
    half8_t af[4], bf[4];
#pragma unroll
    for (int i = 0; i < 4; i++) {
      af[i] = *(const half8_t*)&As[offA[i]];
      bf[i] = *(const half8_t*)&Bs[offB[i]];
    }
#pragma unroll
    for (int i = 0; i < 4; i++)
#pragma unroll
      for (int j = 0; j < 4; j++)
        acc[i][j] = __builtin_amdgcn_mfma_f32_16x16x32_f16(af[i], bf[j], acc[i][j], 0, 0, 0);
  }

  const int rowblk = blockIdx.x * 128;
  const int colblk = blockIdx.y * 128;
  if constexpr (EPI == 1) {
    // 4 passes of 32 output rows, staged through smem (32 x 136 fp16, padded)
    _Float16* C = (_Float16*)CoutAll + (size_t)e * ROWS_PER_E * NDIM;
#pragma unroll
    for (int p = 0; p < 4; p++) {
      __syncthreads();  // previous pass reads (or K-loop frag reads) done
      const int lr0 = (wave & 1) * 16 + quad * 4;
#pragma unroll
      for (int j = 0; j < 4; j++) {
        const int col = wn + j * 16 + ln;
        const float bcol = bias[colblk + col];
#pragma unroll
        for (int r = 0; r < 4; r++) {
          float v = acc[p][j][r] + bcol;
          smem[(lr0 + r) * 136 + col] = (_Float16)fast_gelu(v);
        }
      }
      __syncthreads();
#pragma unroll
      for (int q = 0; q < 2; q++) {
        const int lrw = q * 16 + (tid >> 4);
        const int chunk = tid & 15;
        const int gr = (lrw >= 16 ? 64 : 0) + p * 16 + (lrw & 15);
        float4 vv = *(const float4*)&smem[lrw * 136 + chunk * 8];
        *(float4*)&C[(size_t)(rowblk + gr) * NDIM + colblk + chunk * 8] = vv;
      }
    }
  } else {
    float* C = (float*)CoutAll + (size_t)e * ROWS_PER_E * NDIM;
    const int colb = colblk + wn + ln;
    const int rowb = rowblk + wm + quad * 4;
#pragma unroll
    for (int j = 0; j < 4; j++) {
      const int col = colb + j * 16;
      const float bcol = bias[wn + j * 16 + ln + colblk - colblk + colblk];  // = bias[col]
#pragma unroll
      for (int i = 0; i < 4; i++) {
#pragma unroll
        for (int r = 0; r < 4; r++) {
          const int row = rowb + i * 16 + r;
          C[(size_t)row * NDIM + col] = acc[i][j][r] + bcol;
        }
      }
    }
  }
}

// ---------------- gated combine scatter ----------------
__global__ __launch_bounds__(256)
void combine_kernel(const float* __restrict__ ye, const int* __restrict__ assign_row,
                    const float* __restrict__ tk_val, float* __restrict__ out) {
  const int t = blockIdx.x;
  const int d = threadIdx.x;
  const int r0 = assign_row[t * 2 + 0];
  const int r1 = assign_row[t * 2 + 1];
  const float g0 = tk_val[t * 2 + 0];
  const float g1 = tk_val[t * 2 + 1];
  const float4* y4 = (const float4*)ye;
  float4 v = make_float4(0.f, 0.f, 0.f, 0.f);
  if (r0 >= 0) {
    float4 a = y4[(size_t)r0 * (D_DIM / 4) + d];
    v.x += g0 * a.x; v.y += g0 * a.y; v.z += g0 * a.z; v.w += g0 * a.w;
  }
  if (r1 >= 0) {
    float4 a = y4[(size_t)r1 * (D_DIM / 4) + d];
    v.x += g1 * a.x; v.y += g1 * a.y; v.z += g1 * a.z; v.w += g1 * a.w;
  }
  ((float4*)out)[(size_t)t * (D_DIM / 4) + d] = v;
}

// ---------------- aux scalar ----------------
__global__ void aux_kernel(const float* __restrict__ gates, float* __restrict__ aux_out) {
  __shared__ float impS[64];
  __shared__ float cvS[8];
  const int t = threadIdx.x;           // 256
  const int pair = t >> 2, part = t & 3;
  const int g = pair >> 3, e = pair & 7;
  float sum = 0.f;
  for (int s = part; s < GRP_SZ; s += 4)
    sum += gates[((size_t)g * GRP_SZ + s) * 8 + e];
  sum += __shfl_down(sum, 1, 64);
  sum += __shfl_down(sum, 2, 64);
  if (part == 0) impS[pair] = sum;
  __syncthreads();
  if (t < 8) {
    float mean = 0.f;
    for (int k = 0; k < 8; k++) mean += impS[t * 8 + k];
    mean *= 0.125f;
    float var = 0.f;
    for (int k = 0; k < 8; k++) { float dd = impS[t * 8 + k] - mean; var += dd * dd; }
    var *= 0.125f;
    cvS[t] = var / (mean * mean);
  }
  __syncthreads();
  if (t == 0) {
    float a = 0.f;
    for (int k = 0; k < 8; k++) a += cvS[k];
    aux_out[0] = a * 0.125f;
  }
}

extern "C" void kernel_launch(void* const* d_in, const int* in_sizes, int n_in,
                              void* d_out, int out_size, void* d_ws, size_t ws_size,
                              hipStream_t stream) {
  const float* x  = (const float*)d_in[0];
  const float* wr = (const float*)d_in[1];
  const float* w1 = (const float*)d_in[2];
  const float* b1 = (const float*)d_in[3];
  const float* w2 = (const float*)d_in[4];
  const float* b2 = (const float*)d_in[5];
  float* out = (float*)d_out;

  char* ws = (char*)d_ws;
  size_t off = 0;
  auto alloc = [&](size_t bytes) -> void* {
    void* p = ws + off;
    off += (bytes + 255) & ~(size_t)255;
    return p;
  };
  float*     gates      = (float*)alloc((size_t)N_TOK * 8 * 4);
  int*       tk_idx     = (int*)  alloc((size_t)N_TOK * 2 * 4);
  float*     tk_val     = (float*)alloc((size_t)N_TOK * 2 * 4);
  int*       assign_row = (int*)  alloc((size_t)N_TOK * 2 * 4);
  int*       slot_src   = (int*)  alloc((size_t)SLOT_ROWS * 4);
  _Float16*  A1  = (_Float16*)alloc((size_t)SLOT_ROWS * D_DIM * 2);
  _Float16*  w1t = (_Float16*)alloc((size_t)E_EXP * M_DIM * D_DIM * 2);
  _Float16*  w2t = (_Float16*)alloc((size_t)E_EXP * D_DIM * M_DIM * 2);
  _Float16*  H   = (_Float16*)alloc((size_t)SLOT_ROWS * M_DIM * 2);
  float*     ye  = (float*)   alloc((size_t)SLOT_ROWS * D_DIM * 4);
  if (off > ws_size) return;

  router_kernel<<<N_TOK / 4, 256, 0, stream>>>(x, wr, gates, tk_idx, tk_val);
  scan_kernel<<<N_GRP, 64, 0, stream>>>(tk_idx, slot_src, assign_row);
  gather_kernel<<<SLOT_ROWS, 256, 0, stream>>>(x, slot_src, A1);
  transpose_to_fp16_kernel<<<dim3(M_DIM / 32, D_DIM / 32, E_EXP), 256, 0, stream>>>(w1, w1t, D_DIM, M_DIM);
  transpose_to_fp16_kernel<<<dim3(D_DIM / 32, M_DIM / 32, E_EXP), 256, 0, stream>>>(w2, w2t, M_DIM, D_DIM);
  gemm_bt_kernel<D_DIM, M_DIM, 1><<<dim3(ROWS_PER_E / 128, M_DIM / 128, E_EXP), 256, 0, stream>>>(A1, w1t, b1, H);
  gemm_bt_kernel<M_DIM, D_DIM, 2><<<dim3(ROWS_PER_E / 128, D_DIM / 128, E_EXP), 256, 0, stream>>>(H, w2t, b2, ye);
  combine_kernel<<<N_TOK, 256, 0, stream>>>(ye, assign_row, tk_val, out);
  aux_kernel<<<1, 256, 0, stream>>>(gates, out + (size_t)N_TOK * D_DIM);
}

// Round 3
// 801.894 us; speedup vs baseline: 1.1801x; 1.1367x over previous
//
#include <hip/hip_runtime.h>

// ---- problem constants ----
#define D_DIM 1024
#define E_EXP 8
#define M_DIM 4096
#define N_GRP 8
#define GRP_SZ 1024
#define CAPACITY 256
#define N_TOK (N_GRP * GRP_SZ)                 // 8192 tokens
#define SLOT_ROWS (E_EXP * N_GRP * CAPACITY)   // 16384 expert-slot rows
#define ROWS_PER_E (N_GRP * CAPACITY)          // 2048 rows per expert

typedef _Float16 half8_t __attribute__((ext_vector_type(8)));
typedef float f32x4_t __attribute__((ext_vector_type(4)));

__device__ __forceinline__ void async_copy16(void* lds, const void* gptr) {
  __builtin_amdgcn_global_load_lds(
      (__attribute__((address_space(1))) void*)(void*)(const_cast<void*>(gptr)),
      (__attribute__((address_space(3))) void*)lds,
      16, 0, 0);
}

// fast exact-form tanh-gelu: tanh(w) = 1 - 2/(1+e^{2w}); e^x via v_exp_f32
__device__ __forceinline__ float fast_gelu(float v) {
  float w2 = 1.5957691216057308f * (v + 0.044715f * v * v * v);
  float ex = __expf(w2);
  float t = 1.0f - 2.0f * __builtin_amdgcn_rcpf(1.0f + ex);
  return 0.5f * v * (1.0f + t);
}

// ---------------- router: logits -> softmax -> top2 ----------------
__global__ __launch_bounds__(256)
void router_kernel(const float* __restrict__ x, const float* __restrict__ wr,
                   float* __restrict__ gates, int* __restrict__ tk_idx,
                   float* __restrict__ tk_val) {
  __shared__ __attribute__((aligned(16))) float wrT[E_EXP * D_DIM];
  const int tid = threadIdx.x;
  for (int i = tid; i < E_EXP * D_DIM; i += 256) {
    int d = i >> 3, e = i & 7;
    wrT[e * D_DIM + d] = wr[i];
  }
  __syncthreads();
  const int wv = tid >> 6, lane = tid & 63;
  const int token = blockIdx.x * 4 + wv;   // one wave per token
  const float4* xr = (const float4*)(x + (size_t)token * D_DIM);
  float lg[8] = {0.f, 0.f, 0.f, 0.f, 0.f, 0.f, 0.f, 0.f};
#pragma unroll
  for (int it = 0; it < 4; it++) {
    float4 v = xr[it * 64 + lane];
#pragma unroll
    for (int e = 0; e < 8; e++) {
      float4 w = *(const float4*)&wrT[e * D_DIM + (it * 64 + lane) * 4];
      lg[e] += v.x * w.x + v.y * w.y + v.z * w.z + v.w * w.w;
    }
  }
#pragma unroll
  for (int off = 32; off > 0; off >>= 1) {
#pragma unroll
    for (int e = 0; e < 8; e++) lg[e] += __shfl_xor(lg[e], off, 64);
  }
  if (lane == 0) {
    float mx = lg[0];
#pragma unroll
    for (int e = 1; e < 8; e++) mx = fmaxf(mx, lg[e]);
    float s = 0.f, g[8];
#pragma unroll
    for (int e = 0; e < 8; e++) { g[e] = expf(lg[e] - mx); s += g[e]; }
    float inv = 1.0f / s;
#pragma unroll
    for (int e = 0; e < 8; e++) { g[e] *= inv; gates[(size_t)token * 8 + e] = g[e]; }
    int i0 = 0; float v0 = g[0];
    for (int e = 1; e < 8; e++) if (g[e] > v0) { v0 = g[e]; i0 = e; }
    int i1 = -1; float v1 = -1.f;
    for (int e = 0; e < 8; e++) if (e != i0 && g[e] > v1) { v1 = g[e]; i1 = e; }
    tk_idx[token * 2 + 0] = i0; tk_idx[token * 2 + 1] = i1;
    tk_val[token * 2 + 0] = v0; tk_val[token * 2 + 1] = v1;
  }
}

// ---------------- capacity scan: exact reference semantics ----------------
__global__ void scan_kernel(const int* __restrict__ tk_idx,
                            int* __restrict__ slot_src,
                            int* __restrict__ assign_row) {
  const int g = blockIdx.x;
  const int lane = threadIdx.x;  // 64 threads = 1 wave
  const unsigned long long below = (1ull << lane) - 1ull;
  // preload all 32 expert ids (independent loads issue together)
  int ev[32];
#pragma unroll
  for (int k = 0; k < 2; k++)
#pragma unroll
    for (int ch = 0; ch < 16; ch++)
      ev[k * 16 + ch] = tk_idx[((size_t)g * GRP_SZ + ch * 64 + lane) * 2 + k];
  int cnt[8] = {0, 0, 0, 0, 0, 0, 0, 0};
#pragma unroll
  for (int k = 0; k < 2; k++) {
#pragma unroll
    for (int ch = 0; ch < 16; ch++) {
      const int s = ch * 64 + lane;
      const int e = ev[k * 16 + ch];
      int pos = 0;
#pragma unroll
      for (int ee = 0; ee < 8; ee++) {
        unsigned long long m = __ballot(e == ee);
        if (e == ee) pos = cnt[ee] + (int)__popcll(m & below);
        cnt[ee] += (int)__popcll(m);   // unclamped (matches reference prev)
      }
      int row = (pos < CAPACITY) ? ((e * N_GRP + g) * CAPACITY + pos) : -1;
      assign_row[((size_t)g * GRP_SZ + s) * 2 + k] = row;
      if (row >= 0) slot_src[row] = s;
    }
  }
  for (int e = 0; e < 8; e++)
    for (int c = lane; c < CAPACITY; c += 64)
      if (c >= cnt[e]) slot_src[(e * N_GRP + g) * CAPACITY + c] = -1;
}

// ---------------- gather tokens into fp16 expert rows ----------------
__global__ __launch_bounds__(256)
void gather_kernel(const float* __restrict__ x, const int* __restrict__ slot_src,
                   _Float16* __restrict__ A1) {
  const int row = blockIdx.x;
  const int g = (row >> 8) & 7;
  const int t = threadIdx.x;
  const int s = slot_src[row];
  float2* dst = (float2*)(A1 + (size_t)row * D_DIM);
  if (s < 0) { dst[t] = make_float2(0.f, 0.f); return; }
  const float4 v = ((const float4*)x)[((size_t)g * GRP_SZ + s) * (D_DIM / 4) + t];
  union { _Float16 h[4]; float2 f2; } u;
  u.h[0] = (_Float16)v.x; u.h[1] = (_Float16)v.y;
  u.h[2] = (_Float16)v.z; u.h[3] = (_Float16)v.w;
  dst[t] = u.f2;
}

// ---------------- fp32 (E,R,C) -> fp16 (E,C,R) transpose ----------------
// single pass: float4 global read, float2 store
__global__ __launch_bounds__(256)
void transpose_to_fp16_kernel(const float* __restrict__ src, _Float16* __restrict__ dst,
                              int R, int C) {
  __shared__ float tile[32][33];
  const int e = blockIdx.z;
  const int c0 = blockIdx.x * 32, r0 = blockIdx.y * 32;
  const float* sp = src + (size_t)e * R * C;
  _Float16* dp = dst + (size_t)e * R * C;
  {
    const int row = threadIdx.x >> 3;        // 0..31
    const int cb = (threadIdx.x & 7) * 4;    // 0,4,..28
    float4 v = *(const float4*)&sp[(size_t)(r0 + row) * C + c0 + cb];
    tile[row][cb + 0] = v.x; tile[row][cb + 1] = v.y;
    tile[row][cb + 2] = v.z; tile[row][cb + 3] = v.w;
  }
  __syncthreads();
  const int cl = threadIdx.x >> 3;   // output row (c)
  const int ch = threadIdx.x & 7;    // chunk of 4 fp16
  union { _Float16 h[4]; float2 f2; } u;
#pragma unroll
  for (int k = 0; k < 4; k++) u.h[k] = (_Float16)tile[ch * 4 + k][cl];
  *(float2*)&dp[(size_t)(c0 + cl) * R + r0 + ch * 4] = u.f2;
}

// ---------------- MFMA GEMM: C(2048xN) = A(2048xK) * BT(NxK)^T ----------------
// 128x128 tile, BK=64, 4 waves x (4x4) mfma_f32_16x16x32_f16, 32 MFMA/barrier.
// Flattened grid, yt fastest -> consecutive blocks share the A row-panel
// (A streams from HBM once; B panels stay L3-resident).
// LDS: row = 64 halfs = 8 chunks of 16B; slot c holds global chunk c^(row&7)
// so both DMA (wave-uniform base + lane*16) and fragment ds_read_b128 work
// conflict-free (2 lanes/bank max).
// EPI==1: fast-gelu(acc+bias) -> LDS-staged coalesced fp16 store (H).
// EPI==2: acc+bias -> fp32 direct store (ye).
template <int KDIM, int NDIM, int EPI>
__global__ __launch_bounds__(256)
void gemm_bt_kernel(const _Float16* __restrict__ Aall,
                    const _Float16* __restrict__ BTall,
                    const float* __restrict__ biasAll,
                    void* __restrict__ CoutAll) {
  const int e = blockIdx.z;
  const _Float16* A = Aall + (size_t)e * ROWS_PER_E * KDIM;
  const _Float16* BT = BTall + (size_t)e * NDIM * KDIM;
  const float* bias = biasAll + (size_t)e * NDIM;

  constexpr int NYT = NDIM / 128;
  const int yt = blockIdx.x % NYT;
  const int xt = blockIdx.x / NYT;
  const int rowblk = xt * 128;
  const int colblk = yt * 128;

  const int tid = threadIdx.x;
  const int wave = tid >> 6, lane = tid & 63;
  const int wm = (wave & 1) * 64, wn = (wave >> 1) * 64;

  __shared__ __attribute__((aligned(16))) _Float16 smem[2 * 128 * 64];  // 32 KB
  _Float16* As = smem;
  _Float16* Bs = smem + 128 * 64;

  f32x4_t acc[4][4] = {};

  // staging: issue i covers rows [i*32 + wave*8, +8); lane: row=+ (l>>3), slot=l&7
  const int l_r = lane >> 3, l_c = lane & 7;
  const _Float16* gA[4];
  const _Float16* gB[4];
  _Float16* ldsA[4];
  _Float16* ldsB[4];
#pragma unroll
  for (int i = 0; i < 4; i++) {
    const int rbase = i * 32 + wave * 8;
    const int r = rbase + l_r;
    const int q = l_c ^ (r & 7);
    gA[i] = A + (size_t)(rowblk + r) * KDIM + q * 8;
    gB[i] = BT + (size_t)(colblk + r) * KDIM + q * 8;
    ldsA[i] = &As[rbase * 64];
    ldsB[i] = &Bs[rbase * 64];
  }

  // fragment LDS offsets (h=0 half; h=1 is ^32 elements = chunk^4)
  const int quad = lane >> 4;
  const int ln = lane & 15;
  int offA[4], offB[4];
#pragma unroll
  for (int i = 0; i < 4; i++) {
    int m = wm + i * 16 + ln;
    offA[i] = m * 64 + (quad ^ (m & 7)) * 8;
    int n = wn + i * 16 + ln;
    offB[i] = n * 64 + (quad ^ (n & 7)) * 8;
  }

  for (int kt = 0; kt < KDIM; kt += 64) {
    __syncthreads();
#pragma unroll
    for (int i = 0; i < 4; i++) async_copy16(ldsA[i], gA[i] + kt);
#pragma unroll
    for (int i = 0; i < 4; i++) async_copy16(ldsB[i], gB[i] + kt);
    __syncthreads();
#pragma unroll
    for (int h = 0; h < 2; h++) {
      half8_t af[4], bf[4];
#pragma unroll
      for (int i = 0; i < 4; i++) {
        af[i] = *(const half8_t*)&As[offA[i] ^ (h * 32)];
        bf[i] = *(const half8_t*)&Bs[offB[i] ^ (h * 32)];
      }
#pragma unroll
      for (int i = 0; i < 4; i++)
#pragma unroll
        for (int j = 0; j < 4; j++)
          acc[i][j] = __builtin_amdgcn_mfma_f32_16x16x32_f16(af[i], bf[j], acc[i][j], 0, 0, 0);
    }
  }

  if constexpr (EPI == 1) {
    // 4 passes of 32 output rows, staged through smem (32 x 136 fp16, padded)
    _Float16* C = (_Float16*)CoutAll + (size_t)e * ROWS_PER_E * NDIM;
#pragma unroll
    for (int p = 0; p < 4; p++) {
      __syncthreads();
      const int lr0 = (wave & 1) * 16 + quad * 4;
#pragma unroll
      for (int j = 0; j < 4; j++) {
        const int col = wn + j * 16 + ln;
        const float bcol = bias[colblk + col];
#pragma unroll
        for (int r = 0; r < 4; r++) {
          float v = acc[p][j][r] + bcol;
          smem[(lr0 + r) * 136 + col] = (_Float16)fast_gelu(v);
        }
      }
      __syncthreads();
#pragma unroll
      for (int q = 0; q < 2; q++) {
        const int lrw = q * 16 + (tid >> 4);
        const int chunk = tid & 15;
        const int gr = (lrw >= 16 ? 64 : 0) + p * 16 + (lrw & 15);
        float4 vv = *(const float4*)&smem[lrw * 136 + chunk * 8];
        *(float4*)&C[(size_t)(rowblk + gr) * NDIM + colblk + chunk * 8] = vv;
      }
    }
  } else {
    float* C = (float*)CoutAll + (size_t)e * ROWS_PER_E * NDIM;
    const int colb = colblk + wn + ln;
    const int rowb = rowblk + wm + quad * 4;
#pragma unroll
    for (int j = 0; j < 4; j++) {
      const int col = colb + j * 16;
      const float bcol = bias[col - colblk + colblk];  // = bias[col]
#pragma unroll
      for (int i = 0; i < 4; i++) {
#pragma unroll
        for (int r = 0; r < 4; r++) {
          const int row = rowb + i * 16 + r;
          C[(size_t)row * NDIM + col] = acc[i][j][r] + bcol;
        }
      }
    }
  }
}

// ---------------- gated combine scatter ----------------
__global__ __launch_bounds__(256)
void combine_kernel(const float* __restrict__ ye, const int* __restrict__ assign_row,
                    const float* __restrict__ tk_val, float* __restrict__ out) {
  const int t = blockIdx.x;
  const int d = threadIdx.x;
  const int r0 = assign_row[t * 2 + 0];
  const int r1 = assign_row[t * 2 + 1];
  const float g0 = tk_val[t * 2 + 0];
  const float g1 = tk_val[t * 2 + 1];
  const float4* y4 = (const float4*)ye;
  float4 v = make_float4(0.f, 0.f, 0.f, 0.f);
  if (r0 >= 0) {
    float4 a = y4[(size_t)r0 * (D_DIM / 4) + d];
    v.x += g0 * a.x; v.y += g0 * a.y; v.z += g0 * a.z; v.w += g0 * a.w;
  }
  if (r1 >= 0) {
    float4 a = y4[(size_t)r1 * (D_DIM / 4) + d];
    v.x += g1 * a.x; v.y += g1 * a.y; v.z += g1 * a.z; v.w += g1 * a.w;
  }
  ((float4*)out)[(size_t)t * (D_DIM / 4) + d] = v;
}

// ---------------- aux: stage 1 (64 blocks, one per (g,e)) ----------------
__global__ __launch_bounds__(256)
void aux1_kernel(const float* __restrict__ gates, float* __restrict__ imp) {
  const int g = blockIdx.x >> 3, e = blockIdx.x & 7;
  const int tid = threadIdx.x, lane = tid & 63, wave = tid >> 6;
  float s = 0.f;
  for (int t = tid; t < GRP_SZ; t += 256)
    s += gates[((size_t)g * GRP_SZ + t) * 8 + e];
#pragma unroll
  for (int off = 32; off > 0; off >>= 1) s += __shfl_xor(s, off, 64);
  __shared__ float ws4[4];
  if (lane == 0) ws4[wave] = s;
  __syncthreads();
  if (tid == 0) imp[blockIdx.x] = ws4[0] + ws4[1] + ws4[2] + ws4[3];
}

// ---------------- aux: stage 2 (tiny) ----------------
__global__ void aux2_kernel(const float* __restrict__ imp, float* __restrict__ aux_out) {
  const int t = threadIdx.x;  // 64
  __shared__ float cvS[8];
  if (t < 8) {
    float mean = 0.f;
    for (int k = 0; k < 8; k++) mean += imp[t * 8 + k];
    mean *= 0.125f;
    float var = 0.f;
    for (int k = 0; k < 8; k++) { float dd = imp[t * 8 + k] - mean; var += dd * dd; }
    var *= 0.125f;
    cvS[t] = var / (mean * mean);
  }
  __syncthreads();
  if (t == 0) {
    float a = 0.f;
    for (int k = 0; k < 8; k++) a += cvS[k];
    aux_out[0] = a * 0.125f;
  }
}

extern "C" void kernel_launch(void* const* d_in, const int* in_sizes, int n_in,
                              void* d_out, int out_size, void* d_ws, size_t ws_size,
                              hipStream_t stream) {
  const float* x  = (const float*)d_in[0];
  const float* wr = (const float*)d_in[1];
  const float* w1 = (const float*)d_in[2];
  const float* b1 = (const float*)d_in[3];
  const float* w2 = (const float*)d_in[4];
  const float* b2 = (const float*)d_in[5];
  float* out = (float*)d_out;

  char* ws = (char*)d_ws;
  size_t off = 0;
  auto alloc = [&](size_t bytes) -> void* {
    void* p = ws + off;
    off += (bytes + 255) & ~(size_t)255;
    return p;
  };
  float*     gates      = (float*)alloc((size_t)N_TOK * 8 * 4);
  int*       tk_idx     = (int*)  alloc((size_t)N_TOK * 2 * 4);
  float*     tk_val     = (float*)alloc((size_t)N_TOK * 2 * 4);
  int*       assign_row = (int*)  alloc((size_t)N_TOK * 2 * 4);
  int*       slot_src   = (int*)  alloc((size_t)SLOT_ROWS * 4);
  float*     imp        = (float*)alloc(64 * 4);
  _Float16*  A1  = (_Float16*)alloc((size_t)SLOT_ROWS * D_DIM * 2);
  _Float16*  w1t = (_Float16*)alloc((size_t)E_EXP * M_DIM * D_DIM * 2);
  _Float16*  w2t = (_Float16*)alloc((size_t)E_EXP * D_DIM * M_DIM * 2);
  _Float16*  H   = (_Float16*)alloc((size_t)SLOT_ROWS * M_DIM * 2);
  float*     ye  = (float*)   alloc((size_t)SLOT_ROWS * D_DIM * 4);
  if (off > ws_size) return;

  router_kernel<<<N_TOK / 4, 256, 0, stream>>>(x, wr, gates, tk_idx, tk_val);
  scan_kernel<<<N_GRP, 64, 0, stream>>>(tk_idx, slot_src, assign_row);
  gather_kernel<<<SLOT_ROWS, 256, 0, stream>>>(x, slot_src, A1);
  transpose_to_fp16_kernel<<<dim3(M_DIM / 32, D_DIM / 32, E_EXP), 256, 0, stream>>>(w1, w1t, D_DIM, M_DIM);
  transpose_to_fp16_kernel<<<dim3(D_DIM / 32, M_DIM / 32, E_EXP), 256, 0, stream>>>(w2, w2t, M_DIM, D_DIM);
  gemm_bt_kernel<D_DIM, M_DIM, 1><<<dim3((ROWS_PER_E / 128) * (M_DIM / 128), 1, E_EXP), 256, 0, stream>>>(A1, w1t, b1, H);
  gemm_bt_kernel<M_DIM, D_DIM, 2><<<dim3((ROWS_PER_E / 128) * (D_DIM / 128), 1, E_EXP), 256, 0, stream>>>(H, w2t, b2, ye);
  combine_kernel<<<N_TOK, 256, 0, stream>>>(ye, assign_row, tk_val, out);
  aux1_kernel<<<64, 256, 0, stream>>>(gates, imp);
  aux2_kernel<<<1, 64, 0, stream>>>(imp, out + (size_t)N_TOK * D_DIM);
}

// Round 4
// 749.326 us; speedup vs baseline: 1.2629x; 1.0702x over previous
//
#include <hip/hip_runtime.h>

// ---- problem constants ----
#define D_DIM 1024
#define E_EXP 8
#define M_DIM 4096
#define N_GRP 8
#define GRP_SZ 1024
#define CAPACITY 256
#define N_TOK (N_GRP * GRP_SZ)                 // 8192 tokens
#define SLOT_ROWS (E_EXP * N_GRP * CAPACITY)   // 16384 expert-slot rows
#define ROWS_PER_E (N_GRP * CAPACITY)          // 2048 rows per expert

typedef _Float16 half8_t __attribute__((ext_vector_type(8)));
typedef float f32x4_t __attribute__((ext_vector_type(4)));

__device__ __forceinline__ void async_copy16(void* lds, const void* gptr) {
  __builtin_amdgcn_global_load_lds(
      (__attribute__((address_space(1))) void*)(void*)(const_cast<void*>(gptr)),
      (__attribute__((address_space(3))) void*)lds,
      16, 0, 0);
}

// fast exact-form tanh-gelu: tanh(w) = 1 - 2/(1+e^{2w}); e^x via v_exp_f32
__device__ __forceinline__ float fast_gelu(float v) {
  float w2 = 1.5957691216057308f * (v + 0.044715f * v * v * v);
  float ex = __expf(w2);
  float t = 1.0f - 2.0f * __builtin_amdgcn_rcpf(1.0f + ex);
  return 0.5f * v * (1.0f + t);
}

// ---------------- router: logits -> softmax -> top2 ----------------
__global__ __launch_bounds__(256)
void router_kernel(const float* __restrict__ x, const float* __restrict__ wr,
                   float* __restrict__ gates, int* __restrict__ tk_idx,
                   float* __restrict__ tk_val) {
  __shared__ __attribute__((aligned(16))) float wrT[E_EXP * D_DIM];
  const int tid = threadIdx.x;
  for (int i = tid; i < E_EXP * D_DIM; i += 256) {
    int d = i >> 3, e = i & 7;
    wrT[e * D_DIM + d] = wr[i];
  }
  __syncthreads();
  const int wv = tid >> 6, lane = tid & 63;
  const int token = blockIdx.x * 4 + wv;   // one wave per token
  const float4* xr = (const float4*)(x + (size_t)token * D_DIM);
  float lg[8] = {0.f, 0.f, 0.f, 0.f, 0.f, 0.f, 0.f, 0.f};
#pragma unroll
  for (int it = 0; it < 4; it++) {
    float4 v = xr[it * 64 + lane];
#pragma unroll
    for (int e = 0; e < 8; e++) {
      float4 w = *(const float4*)&wrT[e * D_DIM + (it * 64 + lane) * 4];
      lg[e] += v.x * w.x + v.y * w.y + v.z * w.z + v.w * w.w;
    }
  }
#pragma unroll
  for (int off = 32; off > 0; off >>= 1) {
#pragma unroll
    for (int e = 0; e < 8; e++) lg[e] += __shfl_xor(lg[e], off, 64);
  }
  if (lane == 0) {
    float mx = lg[0];
#pragma unroll
    for (int e = 1; e < 8; e++) mx = fmaxf(mx, lg[e]);
    float s = 0.f, g[8];
#pragma unroll
    for (int e = 0; e < 8; e++) { g[e] = expf(lg[e] - mx); s += g[e]; }
    float inv = 1.0f / s;
#pragma unroll
    for (int e = 0; e < 8; e++) { g[e] *= inv; gates[(size_t)token * 8 + e] = g[e]; }
    int i0 = 0; float v0 = g[0];
    for (int e = 1; e < 8; e++) if (g[e] > v0) { v0 = g[e]; i0 = e; }
    int i1 = -1; float v1 = -1.f;
    for (int e = 0; e < 8; e++) if (e != i0 && g[e] > v1) { v1 = g[e]; i1 = e; }
    tk_idx[token * 2 + 0] = i0; tk_idx[token * 2 + 1] = i1;
    tk_val[token * 2 + 0] = v0; tk_val[token * 2 + 1] = v1;
  }
}

// ---------------- capacity scan: exact reference semantics ----------------
__global__ void scan_kernel(const int* __restrict__ tk_idx,
                            int* __restrict__ slot_src,
                            int* __restrict__ assign_row) {
  const int g = blockIdx.x;
  const int lane = threadIdx.x;  // 64 threads = 1 wave
  const unsigned long long below = (1ull << lane) - 1ull;
  int ev[32];
#pragma unroll
  for (int k = 0; k < 2; k++)
#pragma unroll
    for (int ch = 0; ch < 16; ch++)
      ev[k * 16 + ch] = tk_idx[((size_t)g * GRP_SZ + ch * 64 + lane) * 2 + k];
  int cnt[8] = {0, 0, 0, 0, 0, 0, 0, 0};
#pragma unroll
  for (int k = 0; k < 2; k++) {
#pragma unroll
    for (int ch = 0; ch < 16; ch++) {
      const int s = ch * 64 + lane;
      const int e = ev[k * 16 + ch];
      int pos = 0;
#pragma unroll
      for (int ee = 0; ee < 8; ee++) {
        unsigned long long m = __ballot(e == ee);
        if (e == ee) pos = cnt[ee] + (int)__popcll(m & below);
        cnt[ee] += (int)__popcll(m);   // unclamped (matches reference prev)
      }
      int row = (pos < CAPACITY) ? ((e * N_GRP + g) * CAPACITY + pos) : -1;
      assign_row[((size_t)g * GRP_SZ + s) * 2 + k] = row;
      if (row >= 0) slot_src[row] = s;
    }
  }
  for (int e = 0; e < 8; e++)
    for (int c = lane; c < CAPACITY; c += 64)
      if (c >= cnt[e]) slot_src[(e * N_GRP + g) * CAPACITY + c] = -1;
}

// ---------------- gather tokens into fp16 expert rows ----------------
__global__ __launch_bounds__(256)
void gather_kernel(const float* __restrict__ x, const int* __restrict__ slot_src,
                   _Float16* __restrict__ A1) {
  const int row = blockIdx.x;
  const int g = (row >> 8) & 7;
  const int t = threadIdx.x;
  const int s = slot_src[row];
  float2* dst = (float2*)(A1 + (size_t)row * D_DIM);
  if (s < 0) { dst[t] = make_float2(0.f, 0.f); return; }
  const float4 v = ((const float4*)x)[((size_t)g * GRP_SZ + s) * (D_DIM / 4) + t];
  union { _Float16 h[4]; float2 f2; } u;
  u.h[0] = (_Float16)v.x; u.h[1] = (_Float16)v.y;
  u.h[2] = (_Float16)v.z; u.h[3] = (_Float16)v.w;
  dst[t] = u.f2;
}

// ---------------- fp32 (E,R,C) -> fp16 (E,C,R) transpose, both weights ----------------
__global__ __launch_bounds__(256)
void transpose_both_kernel(const float* __restrict__ w1, const float* __restrict__ w2,
                           _Float16* __restrict__ w1t, _Float16* __restrict__ w2t) {
  __shared__ float tile[32][33];
  const int z = blockIdx.y;
  const float* sp;
  _Float16* dp;
  int R, C;
  if (z < 8) { sp = w1 + (size_t)z * D_DIM * M_DIM; dp = w1t + (size_t)z * D_DIM * M_DIM; R = D_DIM; C = M_DIM; }
  else       { sp = w2 + (size_t)(z - 8) * M_DIM * D_DIM; dp = w2t + (size_t)(z - 8) * M_DIM * D_DIM; R = M_DIM; C = D_DIM; }
  const int tiles_x = C >> 5;
  const int c0 = (blockIdx.x % tiles_x) * 32, r0 = (blockIdx.x / tiles_x) * 32;
  {
    const int row = threadIdx.x >> 3;        // 0..31
    const int cb = (threadIdx.x & 7) * 4;    // 0,4,..28
    float4 v = *(const float4*)&sp[(size_t)(r0 + row) * C + c0 + cb];
    tile[row][cb + 0] = v.x; tile[row][cb + 1] = v.y;
    tile[row][cb + 2] = v.z; tile[row][cb + 3] = v.w;
  }
  __syncthreads();
  const int cl = threadIdx.x >> 3;   // output row (c)
  const int ch = threadIdx.x & 7;    // chunk of 4 fp16
  union { _Float16 h[4]; float2 f2; } u;
#pragma unroll
  for (int k = 0; k < 4; k++) u.h[k] = (_Float16)tile[ch * 4 + k][cl];
  *(float2*)&dp[(size_t)(c0 + cl) * R + r0 + ch * 4] = u.f2;
}

// ---------------- MFMA GEMM: C(2048xN) = A(2048xK) * BT(NxK)^T ----------------
// 128x128 tile, BK=64, 4 waves x (4x4) mfma_f32_16x16x32_f16.
// DOUBLE-BUFFERED K-loop, one barrier per iter: prefetch tile k+1 via
// global_load_lds into the other buffer while computing tile k; the barrier's
// vmcnt(0) drain then waits on loads issued a full compute-phase earlier.
// Four distinct __shared__ arrays + pointer swap to keep alias analysis from
// serializing the prefetch against the current tile's ds_reads.
// LDS swizzle: row = 8 chunks of 16B; slot c holds global chunk c^(row&7).
// EPI==1: fast-gelu(acc+bias) -> LDS-staged coalesced fp16 store (H).
// EPI==2: acc+bias -> fp32 direct store (ye).
template <int KDIM, int NDIM, int EPI>
__global__ __launch_bounds__(256)
void gemm_bt_kernel(const _Float16* __restrict__ Aall,
                    const _Float16* __restrict__ BTall,
                    const float* __restrict__ biasAll,
                    void* __restrict__ CoutAll) {
  const int e = blockIdx.z;
  const _Float16* A = Aall + (size_t)e * ROWS_PER_E * KDIM;
  const _Float16* BT = BTall + (size_t)e * NDIM * KDIM;
  const float* bias = biasAll + (size_t)e * NDIM;

  constexpr int NYT = NDIM / 128;
  const int yt = blockIdx.x % NYT;
  const int xt = blockIdx.x / NYT;
  const int rowblk = xt * 128;
  const int colblk = yt * 128;

  const int tid = threadIdx.x;
  const int wave = tid >> 6, lane = tid & 63;
  const int wm = (wave & 1) * 64, wn = (wave >> 1) * 64;

  __shared__ __attribute__((aligned(16))) _Float16 As0[128 * 64];
  __shared__ __attribute__((aligned(16))) _Float16 As1[128 * 64];
  __shared__ __attribute__((aligned(16))) _Float16 Bs0[128 * 64];
  __shared__ __attribute__((aligned(16))) _Float16 Bs1[128 * 64];

  f32x4_t acc[4][4] = {};

  // staging: issue i covers rows [i*32 + wave*8, +8); lane: row=+(l>>3), slot=l&7
  const int l_r = lane >> 3, l_c = lane & 7;
  const _Float16* gA[4];
  const _Float16* gB[4];
  int ldsOff[4];
#pragma unroll
  for (int i = 0; i < 4; i++) {
    const int rbase = i * 32 + wave * 8;
    const int r = rbase + l_r;
    const int q = l_c ^ (r & 7);
    gA[i] = A + (size_t)(rowblk + r) * KDIM + q * 8;
    gB[i] = BT + (size_t)(colblk + r) * KDIM + q * 8;
    ldsOff[i] = rbase * 64;
  }

  // fragment LDS offsets (h=0 half; h=1 is ^32 elements = chunk^4)
  const int quad = lane >> 4;
  const int ln = lane & 15;
  int offA[4], offB[4];
#pragma unroll
  for (int i = 0; i < 4; i++) {
    int m = wm + i * 16 + ln;
    offA[i] = m * 64 + (quad ^ (m & 7)) * 8;
    int n = wn + i * 16 + ln;
    offB[i] = n * 64 + (quad ^ (n & 7)) * 8;
  }

  _Float16* curA = As0; _Float16* nxtA = As1;
  _Float16* curB = Bs0; _Float16* nxtB = Bs1;

  // prologue: DMA tile 0 into cur
#pragma unroll
  for (int i = 0; i < 4; i++) async_copy16(curA + ldsOff[i], gA[i]);
#pragma unroll
  for (int i = 0; i < 4; i++) async_copy16(curB + ldsOff[i], gB[i]);

  for (int kt = 0; kt < KDIM; kt += 64) {
    __syncthreads();  // drains vmcnt: tile kt (issued last iter) now visible
    if (kt + 64 < KDIM) {
#pragma unroll
      for (int i = 0; i < 4; i++) async_copy16(nxtA + ldsOff[i], gA[i] + kt + 64);
#pragma unroll
      for (int i = 0; i < 4; i++) async_copy16(nxtB + ldsOff[i], gB[i] + kt + 64);
    }
#pragma unroll
    for (int h = 0; h < 2; h++) {
      half8_t af[4], bf[4];
#pragma unroll
      for (int i = 0; i < 4; i++) {
        af[i] = *(const half8_t*)&curA[offA[i] ^ (h * 32)];
        bf[i] = *(const half8_t*)&curB[offB[i] ^ (h * 32)];
      }
#pragma unroll
      for (int i = 0; i < 4; i++)
#pragma unroll
        for (int j = 0; j < 4; j++)
          acc[i][j] = __builtin_amdgcn_mfma_f32_16x16x32_f16(af[i], bf[j], acc[i][j], 0, 0, 0);
    }
    _Float16* t;
    t = curA; curA = nxtA; nxtA = t;
    t = curB; curB = nxtB; nxtB = t;
  }

  if constexpr (EPI == 1) {
    // 4 passes of 32 output rows, staged through As0 (32 x 136 fp16, padded)
    _Float16* C = (_Float16*)CoutAll + (size_t)e * ROWS_PER_E * NDIM;
#pragma unroll
    for (int p = 0; p < 4; p++) {
      __syncthreads();
      const int lr0 = (wave & 1) * 16 + quad * 4;
#pragma unroll
      for (int j = 0; j < 4; j++) {
        const int col = wn + j * 16 + ln;
        const float bcol = bias[colblk + col];
#pragma unroll
        for (int r = 0; r < 4; r++) {
          float v = acc[p][j][r] + bcol;
          As0[(lr0 + r) * 136 + col] = (_Float16)fast_gelu(v);
        }
      }
      __syncthreads();
#pragma unroll
      for (int q = 0; q < 2; q++) {
        const int lrw = q * 16 + (tid >> 4);
        const int chunk = tid & 15;
        const int gr = (lrw >= 16 ? 64 : 0) + p * 16 + (lrw & 15);
        float4 vv = *(const float4*)&As0[lrw * 136 + chunk * 8];
        *(float4*)&C[(size_t)(rowblk + gr) * NDIM + colblk + chunk * 8] = vv;
      }
    }
  } else {
    float* C = (float*)CoutAll + (size_t)e * ROWS_PER_E * NDIM;
    const int colb = colblk + wn + ln;
    const int rowb = rowblk + wm + quad * 4;
#pragma unroll
    for (int j = 0; j < 4; j++) {
      const int col = colb + j * 16;
      const float bcol = bias[col];
#pragma unroll
      for (int i = 0; i < 4; i++) {
#pragma unroll
        for (int r = 0; r < 4; r++) {
          const int row = rowb + i * 16 + r;
          C[(size_t)row * NDIM + col] = acc[i][j][r] + bcol;
        }
      }
    }
  }
}

// ---------------- gated combine scatter ----------------
__global__ __launch_bounds__(256)
void combine_kernel(const float* __restrict__ ye, const int* __restrict__ assign_row,
                    const float* __restrict__ tk_val, float* __restrict__ out) {
  const int t = blockIdx.x;
  const int d = threadIdx.x;
  const int r0 = assign_row[t * 2 + 0];
  const int r1 = assign_row[t * 2 + 1];
  const float g0 = tk_val[t * 2 + 0];
  const float g1 = tk_val[t * 2 + 1];
  const float4* y4 = (const float4*)ye;
  float4 v = make_float4(0.f, 0.f, 0.f, 0.f);
  if (r0 >= 0) {
    float4 a = y4[(size_t)r0 * (D_DIM / 4) + d];
    v.x += g0 * a.x; v.y += g0 * a.y; v.z += g0 * a.z; v.w += g0 * a.w;
  }
  if (r1 >= 0) {
    float4 a = y4[(size_t)r1 * (D_DIM / 4) + d];
    v.x += g1 * a.x; v.y += g1 * a.y; v.z += g1 * a.z; v.w += g1 * a.w;
  }
  ((float4*)out)[(size_t)t * (D_DIM / 4) + d] = v;
}

// ---------------- aux: stage 1 (64 blocks, one per (g,e)) ----------------
__global__ __launch_bounds__(256)
void aux1_kernel(const float* __restrict__ gates, float* __restrict__ imp) {
  const int g = blockIdx.x >> 3, e = blockIdx.x & 7;
  const int tid = threadIdx.x, lane = tid & 63, wave = tid >> 6;
  float s = 0.f;
  for (int t = tid; t < GRP_SZ; t += 256)
    s += gates[((size_t)g * GRP_SZ + t) * 8 + e];
#pragma unroll
  for (int off = 32; off > 0; off >>= 1) s += __shfl_xor(s, off, 64);
  __shared__ float ws4[4];
  if (lane == 0) ws4[wave] = s;
  __syncthreads();
  if (tid == 0) imp[blockIdx.x] = ws4[0] + ws4[1] + ws4[2] + ws4[3];
}

// ---------------- aux: stage 2 (tiny) ----------------
__global__ void aux2_kernel(const float* __restrict__ imp, float* __restrict__ aux_out) {
  const int t = threadIdx.x;  // 64
  __shared__ float cvS[8];
  if (t < 8) {
    float mean = 0.f;
    for (int k = 0; k < 8; k++) mean += imp[t * 8 + k];
    mean *= 0.125f;
    float var = 0.f;
    for (int k = 0; k < 8; k++) { float dd = imp[t * 8 + k] - mean; var += dd * dd; }
    var *= 0.125f;
    cvS[t] = var / (mean * mean);
  }
  __syncthreads();
  if (t == 0) {
    float a = 0.f;
    for (int k = 0; k < 8; k++) a += cvS[k];
    aux_out[0] = a * 0.125f;
  }
}

extern "C" void kernel_launch(void* const* d_in, const int* in_sizes, int n_in,
                              void* d_out, int out_size, void* d_ws, size_t ws_size,
                              hipStream_t stream) {
  const float* x  = (const float*)d_in[0];
  const float* wr = (const float*)d_in[1];
  const float* w1 = (const float*)d_in[2];
  const float* b1 = (const float*)d_in[3];
  const float* w2 = (const float*)d_in[4];
  const float* b2 = (const float*)d_in[5];
  float* out = (float*)d_out;

  char* ws = (char*)d_ws;
  size_t off = 0;
  auto alloc = [&](size_t bytes) -> void* {
    void* p = ws + off;
    off += (bytes + 255) & ~(size_t)255;
    return p;
  };
  float*     gates      = (float*)alloc((size_t)N_TOK * 8 * 4);
  int*       tk_idx     = (int*)  alloc((size_t)N_TOK * 2 * 4);
  float*     tk_val     = (float*)alloc((size_t)N_TOK * 2 * 4);
  int*       assign_row = (int*)  alloc((size_t)N_TOK * 2 * 4);
  int*       slot_src   = (int*)  alloc((size_t)SLOT_ROWS * 4);
  float*     imp        = (float*)alloc(64 * 4);
  _Float16*  A1  = (_Float16*)alloc((size_t)SLOT_ROWS * D_DIM * 2);
  _Float16*  w1t = (_Float16*)alloc((size_t)E_EXP * M_DIM * D_DIM * 2);
  _Float16*  w2t = (_Float16*)alloc((size_t)E_EXP * D_DIM * M_DIM * 2);
  _Float16*  H   = (_Float16*)alloc((size_t)SLOT_ROWS * M_DIM * 2);
  float*     ye  = (float*)   alloc((size_t)SLOT_ROWS * D_DIM * 4);
  if (off > ws_size) return;

  router_kernel<<<N_TOK / 4, 256, 0, stream>>>(x, wr, gates, tk_idx, tk_val);
  scan_kernel<<<N_GRP, 64, 0, stream>>>(tk_idx, slot_src, assign_row);
  gather_kernel<<<SLOT_ROWS, 256, 0, stream>>>(x, slot_src, A1);
  transpose_both_kernel<<<dim3(4096, 16), 256, 0, stream>>>(w1, w2, w1t, w2t);
  gemm_bt_kernel<D_DIM, M_DIM, 1><<<dim3((ROWS_PER_E / 128) * (M_DIM / 128), 1, E_EXP), 256, 0, stream>>>(A1, w1t, b1, H);
  gemm_bt_kernel<M_DIM, D_DIM, 2><<<dim3((ROWS_PER_E / 128) * (D_DIM / 128), 1, E_EXP), 256, 0, stream>>>(H, w2t, b2, ye);
  combine_kernel<<<N_TOK, 256, 0, stream>>>(ye, assign_row, tk_val, out);
  aux1_kernel<<<64, 256, 0, stream>>>(gates, imp);
  aux2_kernel<<<1, 64, 0, stream>>>(imp, out + (size_t)N_TOK * D_DIM);
}